// Round 13
// baseline (100.267 us; speedup 1.0000x reference)
//
#include <hip/hip_runtime.h>

#define INF 1e10f
#define EPSV 1e-5f
#define NB 2
#define NN 512
#define NF 64
#define NH 64
#define NCC 32
#define NRBF 50
#define NND (NB*NN)
#define MU_STEP (5.0f/49.0f)
#define C20S (20.f*MU_STEP)

typedef _Float16 half8 __attribute__((ext_vector_type(8)));
typedef float f32x4 __attribute__((ext_vector_type(4)));

__device__ __forceinline__ float frcp(float x){ return __builtin_amdgcn_rcpf(x); }
__device__ __forceinline__ float silu_f(float x){ return x * frcp(1.f + __expf(-x)); }
// tanh(x) = 1 - 2/(1+e^{2x}); saturates cleanly at +/-inf (rcp(inf)=0)
__device__ __forceinline__ float tanh_f(float x){
  float t = __expf(2.f * x);
  return fmaf(-2.f, frcp(t + 1.f), 1.f);
}

__device__ __forceinline__ float wredSum(float v){
  v += __shfl_down(v, 32); v += __shfl_down(v, 16); v += __shfl_down(v, 8);
  v += __shfl_down(v, 4);  v += __shfl_down(v, 2);  v += __shfl_down(v, 1);
  return v;
}
__device__ __forceinline__ float bredSum(float v, float* red, int tid){
  float w = wredSum(v);
  __syncthreads();
  if ((tid & 63) == 0) red[tid >> 6] = w;
  __syncthreads();
  return (red[0] + red[1]) + (red[2] + red[3]);
}
__device__ __forceinline__ float2 bredSum2(float a, float b, float* red, int tid){
  float wa = wredSum(a), wb = wredSum(b);
  __syncthreads();
  if ((tid & 63) == 0){ red[(tid >> 6) * 2] = wa; red[(tid >> 6) * 2 + 1] = wb; }
  __syncthreads();
  return make_float2(red[0] + red[2] + red[4] + red[6],
                     red[1] + red[3] + red[5] + red[7]);
}

// -------- Kernel A: per-node projections + fragment packing (fused) -------
// frag: fi 0..7 WfT A-frags (row-permuted so filt C-out == A-frag layout),
//       fi 8..15 Wc1 B-frags, fi 16..19 We3 B-frags
__global__ void kA(const float* __restrict__ h, const float* __restrict__ Wdh,
                   const float* __restrict__ Wew, const float* __restrict__ Wsa,
                   const float* __restrict__ bdh, const float* __restrict__ bew,
                   const float* __restrict__ Wf, const float* __restrict__ bf,
                   const float* __restrict__ Wcm1,
                   float* __restrict__ u, float* __restrict__ vb,
                   float* __restrict__ e1r, float* __restrict__ e2c,
                   float* __restrict__ s1, float* __restrict__ s2,
                   unsigned int* __restrict__ frag){
  const int tid = threadIdx.x;
  const int sub = tid >> 6, l = tid & 63;
  const int node = blockIdx.x * 4 + sub;
  __shared__ float sh[4][NF];
  sh[sub][l] = h[node * NF + l];
  __syncthreads();
  float ua = 0.f, va = 0.f;
  #pragma unroll
  for (int f = 0; f < NF; ++f){
    float hv = sh[sub][f];
    ua = fmaf(hv, Wdh[f * NH + l], ua);
    va = fmaf(hv, Wdh[(NF + f) * NH + l], va);
  }
  u[node * NH + l] = ua;
  vb[node * NH + l] = va + bdh[l];
  const int nc = l & 31;
  const int half = l >> 5;
  float ea = 0.f;
  #pragma unroll
  for (int f = 0; f < NF; ++f) ea = fmaf(sh[sub][f], Wew[(half * NF + f) * NCC + nc], ea);
  if (half == 0) e1r[node * NCC + nc] = ea;
  else           e2c[node * NCC + nc] = ea + bew[nc];
  if (l < 2){
    const float* wp = Wsa + l * NF;
    float s = 0.f;
    #pragma unroll
    for (int f = 0; f < NF; ++f) s = fmaf(sh[sub][f], wp[f], s);
    if (l == 0) s1[node] = s; else s2[node] = s;
  }
  // ---- fragment packing (blocks 0..19 only) ----
  if (blockIdx.x < 20){
    const int fi = blockIdx.x;
    const int lane = tid >> 2, dw = tid & 3;
    float v[2];
    #pragma unroll
    for (int e2 = 0; e2 < 2; ++e2){
      int e = dw * 2 + e2;
      int kk = 8 * (lane >> 4) + e;
      int n16 = lane & 15;
      float val;
      if (fi < 8){
        int mt = fi >> 1, kc = fi & 1;
        int hh = 8 * (n16 >> 2) + (n16 & 3) + 4 * (mt & 1) + 32 * (mt >> 1);
        int r = kk + 32 * kc;
        val = (r < NRBF) ? Wf[r * NH + hh] : ((r == NRBF) ? bf[hh] : 0.f);
      } else if (fi < 16){
        int q = fi - 8; int kc = q >> 2, nt = q & 3;
        val = Wcm1[(kk + 32 * kc) * NH + (n16 + 16 * nt)];
      } else {
        int q = fi - 16; int kc = q >> 1, n2 = q & 1;
        val = Wew[(2 * NF + kk + 32 * kc) * NCC + (n16 + 16 * n2)];
      }
      v[e2] = val;
    }
    unsigned int lo = (unsigned int)__builtin_bit_cast(unsigned short, (_Float16)v[0]);
    unsigned int hi = (unsigned int)__builtin_bit_cast(unsigned short, (_Float16)v[1]);
    frag[fi * 256 + lane * 4 + dw] = lo | (hi << 16);
  }
}

// -------- Kernel B: per-(b,i) edge pass + fused tail MLPs -----------------
__global__ __launch_bounds__(256, 5) void kB(
    const float* __restrict__ x, const float* __restrict__ mask,
    const float* __restrict__ h_g,
    const float* __restrict__ u, const float* __restrict__ vb,
    const float* __restrict__ s1g, const float* __restrict__ s2g,
    const float* __restrict__ e1r, const float* __restrict__ e2c,
    const float* __restrict__ Wc2, const float* __restrict__ bc1, const float* __restrict__ bc2g,
    const unsigned int* __restrict__ frag,
    const float* __restrict__ Wpn1, const float* __restrict__ bpn1,
    const float* __restrict__ Wpn2, const float* __restrict__ bpn2,
    const float* __restrict__ Wnm1, const float* __restrict__ bnm1,
    const float* __restrict__ Wnm2, const float* __restrict__ bnm2,
    float* __restrict__ out)
{
  const int bid = blockIdx.x;
  const int b = bid >> 9, i = bid & (NN - 1);
  const int tid = threadIdx.x;
  const int lane = tid & 63, wave = tid >> 6;
  const int l15 = lane & 15, g = lane >> 4;
  const int base = b * NN;

  __shared__ __align__(16) float4 s_geo[NN];  // d0*m,d1*m,d2*m,(m?+:-)norm 8KB
  __shared__ float s_tot[NN];                 // tot*m                      2KB
  __shared__ float s_vb[64];                  // vb+bdh for this i          256B
  __shared__ float s_red[8];
  __shared__ half8 s_WB[20][64];              // all weight frags           20KB

  // stage all fragments into LDS (1280 int4) + vb row
  {
    const int4* src = (const int4*)frag;
    int4* dst = (int4*)&s_WB[0][0];
    #pragma unroll
    for (int q = 0; q < 5; ++q) dst[tid + q * 256] = src[tid + q * 256];
    if (tid < 64) s_vb[tid] = vb[(size_t)(base + i) * NH + tid];
  }

  const float xi0 = x[(base + i) * 3 + 0];
  const float xi1 = x[(base + i) * 3 + 1];
  const float xi2 = x[(base + i) * 3 + 2];
  const float s2i = s2g[base + i];

  // ---- pass 1: bounded logits -> direct exp, 2 reduction rounds ----
  float ea[2], es[2], mj[2];
  #pragma unroll
  for (int q = 0; q < 2; ++q){
    const int j = tid + q * 256;
    float d0 = x[(base + j) * 3 + 0] - xi0;
    float d1 = x[(base + j) * 3 + 1] - xi1;
    float d2 = x[(base + j) * 3 + 2] - xi2;
    float nsq = d0 * d0 + d1 * d1 + d2 * d2;
    float norm = sqrtf(fmaxf(nsq, 0.f) + EPSV);
    float m = mask[(base + i) * NN + j];
    float eye = (j == i) ? 1.f : 0.f;
    // spatial logit <= 0 ; sem logit bounded ; no max-subtraction needed
    ea[q] = __expf(-(norm + eye * INF + (1.f - m) * INF));
    float sp = s1g[base + j] + s2i;
    es[q] = __expf(silu_f(sp) - eye * INF + (m - 1.f) * INF);
    // mask folded into d; m sign-encoded into norm slot
    s_geo[j] = make_float4(d0 * m, d1 * m, d2 * m, (m > 0.5f) ? norm : -norm);
    mj[q] = m;
  }
  float2 S12 = bredSum2(ea[0] + ea[1], es[0] + es[1], s_red, tid);
  const float iS1 = 1.f / S12.x, iS2 = 1.f / S12.y;
  float e3[2];
  #pragma unroll
  for (int q = 0; q < 2; ++q)
    e3[q] = __expf((es[q] * iS2) * (ea[q] * iS1) + (mj[q] - 1.f) * INF);
  float S3 = bredSum(e3[0] + e3[1], s_red, tid);
  const float iS3 = 1.f / S3;
  s_tot[tid]       = e3[0] * iS3 * mj[0];
  s_tot[tid + 256] = e3[1] * iS3 * mj[1];
  __syncthreads();   // covers pass-1 LDS + s_WB/s_vb staging

  // ---- per-i prologue (small constants only; vb stays in LDS) ----
  float wc2v[4], bc1v[4];
  #pragma unroll
  for (int nt = 0; nt < 4; ++nt){ wc2v[nt] = Wc2[l15 + 16*nt]; bc1v[nt] = bc1[l15 + 16*nt]; }
  float e2v[2];
  e2v[0] = e2c[(size_t)(base + i) * NCC + l15];
  e2v[1] = e2c[(size_t)(base + i) * NCC + l15 + 16];
  const float bc2v16 = bc2g[0] * 0.0625f;   // bc2 / 16: added once per edge across 16 lanes
  const float mub0 = (float)(8 * g) * MU_STEP;
  const float mub1 = (float)(8 * g + 32) * MU_STEP;
  // rbf ratio-recurrence constants: e_{r+1} = e_r * rho_r ; rho_{r+1} = rho_r * q
  const float QCONST = __expf(-20.f * MU_STEP * MU_STEP);
  const float crho0 = -10.f * MU_STEP * MU_STEP * (float)(16 * g + 1);
  const float crho1 = -10.f * MU_STEP * MU_STEP * (float)(16 * g + 65);

  float hg[16];
  #pragma unroll
  for (int e = 0; e < 16; ++e) hg[e] = 0.f;
  float at[2][3] = {{0.f,0.f,0.f},{0.f,0.f,0.f}};
  float xa0 = 0.f, xa1 = 0.f, xa2 = 0.f;

  // ---- pass 2: 8 j-tiles of 16 per wave ----
  for (int jt8 = 0; jt8 < 8; ++jt8){
    const int jt = wave * 128 + jt8 * 16;
    const int jl = jt + l15;
    // u loads issued at tile start (covered by rbf chain + filt MFMA issue)
    const float4* up = (const float4*)(u + (size_t)(base + jl) * NH);
    float4 u0 = up[2*g], u1 = up[2*g+1], u2 = up[2*g+8], u3 = up[2*g+9];
    float encw = s_geo[jl].w;
    float normj = fabsf(encw);
    float tmw = s_tot[jl];
    // rbf B-frags via ratio recurrence: 4 exps + 28 muls
    half8 brb[2];
    {
      float d0 = normj - mub0;
      float d1 = normj - mub1;
      float e0 = __expf(-10.f * d0 * d0);
      float e1 = __expf(-10.f * d1 * d1);
      float r0a = __expf(fmaf(C20S, normj, crho0));
      float r1a = __expf(fmaf(C20S, normj, crho1));
      const int rbase1 = 8*g + 32;
      brb[0][0] = (_Float16)e0;
      brb[1][0] = (_Float16)((rbase1 < NRBF) ? e1 : ((rbase1 == NRBF) ? 1.f : 0.f));
      #pragma unroll
      for (int rr = 1; rr < 8; ++rr){
        e0 *= r0a;  r0a *= QCONST;
        e1 *= r1a;  r1a *= QCONST;
        int r1i = rbase1 + rr;
        brb[0][rr] = (_Float16)e0;
        brb[1][rr] = (_Float16)((r1i < NRBF) ? e1 : ((r1i == NRBF) ? 1.f : 0.f));
      }
    }
    // filtT = WfT(perm) @ rbfT : C-output IS the A-frag layout
    f32x4 fc[4];
    __builtin_amdgcn_s_setprio(1);
    #pragma unroll
    for (int mt = 0; mt < 4; ++mt){
      f32x4 z = {0.f,0.f,0.f,0.f};
      z = __builtin_amdgcn_mfma_f32_16x16x32_f16(s_WB[2*mt][lane],   brb[0], z, 0, 0, 0);
      z = __builtin_amdgcn_mfma_f32_16x16x32_f16(s_WB[2*mt+1][lane], brb[1], z, 0, 0, 0);
      fc[mt] = z;
    }
    __builtin_amdgcn_s_setprio(0);
    // vb re-read from LDS each tile (index laundered so LICM can't hoist)
    int vbi = 8 * g;
    asm volatile("" : "+v"(vbi));
    const float4* vb4 = (const float4*)(s_vb + vbi);
    float4 b0v = vb4[0], b1v = vb4[1], b2v = vb4[8], b3v = vb4[9];
    float bv[16] = {b0v.x,b0v.y,b0v.z,b0v.w, b1v.x,b1v.y,b1v.z,b1v.w,
                    b2v.x,b2v.y,b2v.z,b2v.w, b3v.x,b3v.y,b3v.z,b3v.w};
    float ua[16] = {u0.x,u0.y,u0.z,u0.w, u1.x,u1.y,u1.z,u1.w,
                    u2.x,u2.y,u2.z,u2.w, u3.x,u3.y,u3.z,u3.w};
    float FH[16];
    half8 afh[2];
    #pragma unroll
    for (int kc = 0; kc < 2; ++kc)
      #pragma unroll
      for (int e = 0; e < 8; ++e){
        int el = kc*8 + e;
        float f = fc[2*kc + (e>>2)][e & 3];
        FH[el] = (ua[el] + bv[el]) * f;
        afh[kc][e] = (_Float16)FH[el];
      }
    #pragma unroll
    for (int e = 0; e < 16; ++e) hg[e] = fmaf(tmw, FH[e], hg[e]);
    // e1 loads (consumed by tanh at tile end; issued before MFMAs)
    float e1v[4][2];
    #pragma unroll
    for (int reg = 0; reg < 4; ++reg){
      const float* ep1 = e1r + (size_t)(base + jt + 4*g + reg) * NCC + l15;
      e1v[reg][0] = ep1[0]; e1v[reg][1] = ep1[16];
    }
    // CM = FH @ Wc1 ; EW = FH @ We3 (frags from LDS)
    f32x4 cm[4];
    f32x4 ew[2];
    __builtin_amdgcn_s_setprio(1);
    #pragma unroll
    for (int nt = 0; nt < 4; ++nt){
      f32x4 z = {0.f,0.f,0.f,0.f};
      z = __builtin_amdgcn_mfma_f32_16x16x32_f16(afh[0], s_WB[8+nt][lane],  z, 0, 0, 0);
      z = __builtin_amdgcn_mfma_f32_16x16x32_f16(afh[1], s_WB[12+nt][lane], z, 0, 0, 0);
      cm[nt] = z;
    }
    #pragma unroll
    for (int n2 = 0; n2 < 2; ++n2){
      f32x4 z = {0.f,0.f,0.f,0.f};
      z = __builtin_amdgcn_mfma_f32_16x16x32_f16(afh[0], s_WB[16+n2][lane], z, 0, 0, 0);
      z = __builtin_amdgcn_mfma_f32_16x16x32_f16(afh[1], s_WB[18+n2][lane], z, 0, 0, 0);
      ew[n2] = z;
    }
    __builtin_amdgcn_s_setprio(0);
    float mreg[4], invr[4]; float4 geo4[4];
    #pragma unroll
    for (int reg = 0; reg < 4; ++reg){
      int jr = jt + 4*g + reg;
      geo4[reg] = s_geo[jr];                 // xyz mask-premultiplied
      float ew_ = geo4[reg].w;
      mreg[reg] = (ew_ > 0.f) ? 1.f : 0.f;   // decode m
      invr[reg] = frcp(fmaf(ew_, ew_, EPSV));// 1/(norm^2+eps); sign irrelevant
    }
    // coordinate MLP: silu + dot(Wc2); 16-lane reduce deferred to final xa
    float hEp[4] = {0.f,0.f,0.f,0.f};
    #pragma unroll
    for (int nt = 0; nt < 4; ++nt)
      #pragma unroll
      for (int reg = 0; reg < 4; ++reg){
        float tv = silu_f(fmaf(mreg[reg], cm[nt][reg], bc1v[nt]));
        hEp[reg] = fmaf(tv, wc2v[nt], hEp[reg]);
      }
    #pragma unroll
    for (int reg = 0; reg < 4; ++reg){
      float hv = hEp[reg] + bc2v16;
      xa0 = fmaf(geo4[reg].x, hv, xa0);
      xa1 = fmaf(geo4[reg].y, hv, xa1);
      xa2 = fmaf(geo4[reg].z, hv, xa2);
    }
    // edge weights: tanh + att accumulation (c = geo*inv, inv folded into wv)
    #pragma unroll
    for (int n2 = 0; n2 < 2; ++n2)
      #pragma unroll
      for (int reg = 0; reg < 4; ++reg){
        float wv = tanh_f(ew[n2][reg] + e1v[reg][n2] + e2v[n2]) * invr[reg];
        at[n2][0] = fmaf(wv, geo4[reg].x, at[n2][0]);
        at[n2][1] = fmaf(wv, geo4[reg].y, at[n2][1]);
        at[n2][2] = fmaf(wv, geo4[reg].z, at[n2][2]);
      }
  }

  // ---- reduces ----
  #pragma unroll
  for (int e = 0; e < 16; ++e){
    float v = hg[e];
    v += __shfl_xor(v, 1); v += __shfl_xor(v, 2);
    v += __shfl_xor(v, 4); v += __shfl_xor(v, 8);
    hg[e] = v;
  }
  #pragma unroll
  for (int n2 = 0; n2 < 2; ++n2)
    #pragma unroll
    for (int d = 0; d < 3; ++d){
      float v = at[n2][d];
      v += __shfl_xor(v, 16); v += __shfl_xor(v, 32);
      at[n2][d] = v;
    }
  // xa holds per-lane partials (hEp deferral) -> full 64-lane reduce
  #pragma unroll
  for (int s = 1; s <= 32; s <<= 1){
    xa0 += __shfl_xor(xa0, s);
    xa1 += __shfl_xor(xa1, s);
    xa2 += __shfl_xor(xa2, s);
  }

  // ---- epilogue across waves (alias s_WB; all frag reads done) ----
  __syncthreads();
  float* ep = (float*)&s_WB[0][0];     // 5120 floats available
  if (l15 == 0){
    #pragma unroll
    for (int e = 0; e < 16; ++e)
      ep[wave*64 + 8*g + (e & 7) + 32*(e >> 3)] = hg[e];
  }
  if (lane < 16){
    #pragma unroll
    for (int n2 = 0; n2 < 2; ++n2)
      #pragma unroll
      for (int d = 0; d < 3; ++d)
        ep[256 + wave*96 + (l15 + 16*n2)*3 + d] = at[n2][d];
  }
  if (lane == 0){
    ep[640 + wave*3 + 0] = xa0; ep[640 + wave*3 + 1] = xa1; ep[640 + wave*3 + 2] = xa2;
  }
  __syncthreads();
  if (tid < 64)
    ep[832 + tid] = ep[tid] + ep[64+tid] + ep[128+tid] + ep[192+tid];   // hga -> LDS
  if (tid >= 64 && tid < 160){
    int t = tid - 64;
    ep[704 + t] = ep[256+t] + ep[352+t] + ep[448+t] + ep[544+t];
  }
  if (tid >= 192 && tid < 195){
    int d = tid - 192;
    out[NB*NN*NH + (base + i)*3 + d] =
        ep[640+d] + ep[643+d] + ep[646+d] + ep[649+d] + x[(base + i)*3 + d];
  }
  __syncthreads();
  if (tid < 32){
    float a0 = ep[704 + tid*3], a1 = ep[704 + tid*3 + 1], a2 = ep[704 + tid*3 + 2];
    ep[896 + tid] = sqrtf(fmaxf(a0*a0 + a1*a1 + a2*a2, 0.f) + EPSV);    // attn -> LDS
  }
  __syncthreads();

  // ---- fused tail MLPs (wave 0 only; sa=ep[896..], sg=ep[832..]) ----
  if (wave == 0){
    const int k = lane;
    const int node = base + i;
    ep[1056 + k] = h_g[node * NF + k];
    asm volatile("s_waitcnt lgkmcnt(0)" ::: "memory");
    __builtin_amdgcn_wave_barrier();
    float acc = bpn1[k];
    #pragma unroll
    for (int t = 0; t < NCC; ++t) acc = fmaf(ep[896 + t], Wpn1[t * NH + k], acc);
    ep[928 + k] = silu_f(acc);
    asm volatile("s_waitcnt lgkmcnt(0)" ::: "memory");
    __builtin_amdgcn_wave_barrier();
    acc = bpn2[k];
    #pragma unroll
    for (int t = 0; t < NH; ++t) acc = fmaf(ep[928 + t], Wpn2[t * NH + k], acc);
    ep[992 + k] = acc;                         // emb
    asm volatile("s_waitcnt lgkmcnt(0)" ::: "memory");
    __builtin_amdgcn_wave_barrier();
    acc = bnm1[k];
    #pragma unroll
    for (int t = 0; t < NF; ++t) acc = fmaf(ep[1056 + t], Wnm1[t * NH + k], acc);
    #pragma unroll
    for (int t = 0; t < NH; ++t) acc = fmaf(ep[832 + t],  Wnm1[(NF + t) * NH + k], acc);
    #pragma unroll
    for (int t = 0; t < NH; ++t) acc = fmaf(ep[992 + t],  Wnm1[(NF + NH + t) * NH + k], acc);
    float srv = silu_f(acc);
    asm volatile("s_waitcnt lgkmcnt(0)" ::: "memory");
    __builtin_amdgcn_wave_barrier();
    ep[928 + k] = srv;
    asm volatile("s_waitcnt lgkmcnt(0)" ::: "memory");
    __builtin_amdgcn_wave_barrier();
    acc = bnm2[k];
    #pragma unroll
    for (int t = 0; t < NH; ++t) acc = fmaf(ep[928 + t], Wnm2[t * NH + k], acc);
    out[node * NH + k] = acc;
  }
}

extern "C" void kernel_launch(void* const* d_in, const int* in_sizes, int n_in,
                              void* d_out, int out_size, void* d_ws, size_t ws_size,
                              hipStream_t stream){
  const float* h    = (const float*)d_in[0];
  const float* x    = (const float*)d_in[1];
  const float* mask = (const float*)d_in[2];
  const float* Wdh  = (const float*)d_in[3];
  const float* bdh  = (const float*)d_in[4];
  const float* Wf   = (const float*)d_in[6];
  const float* bf   = (const float*)d_in[7];
  const float* Wsa  = (const float*)d_in[8];
  const float* Wew  = (const float*)d_in[9];
  const float* bew  = (const float*)d_in[10];
  const float* Wpn1 = (const float*)d_in[11];
  const float* bpn1 = (const float*)d_in[12];
  const float* Wpn2 = (const float*)d_in[13];
  const float* bpn2 = (const float*)d_in[14];
  const float* Wnm1 = (const float*)d_in[15];
  const float* bnm1 = (const float*)d_in[16];
  const float* Wnm2 = (const float*)d_in[17];
  const float* bnm2 = (const float*)d_in[18];
  const float* Wcm1 = (const float*)d_in[19];
  const float* bcm1 = (const float*)d_in[20];
  const float* Wcm2 = (const float*)d_in[21];
  const float* bcm2 = (const float*)d_in[22];
  float* out = (float*)d_out;
  float* ws  = (float*)d_ws;

  float* u    = ws;             // [1024][64]
  float* vbuf = u    + 65536;   // [1024][64]
  float* s1   = vbuf + 65536;   // [1024]
  float* s2   = s1   + 1024;    // [1024]
  float* e1r  = s2   + 1024;    // [1024][32]
  float* e2c  = e1r  + 32768;   // [1024][32]
  unsigned int* fragb = (unsigned int*)(e2c + 32768);   // 20*256 u32

  hipLaunchKernelGGL(kA, dim3(NND / 4), dim3(256), 0, stream,
                     h, Wdh, Wew, Wsa, bdh, bew, Wf, bf, Wcm1,
                     u, vbuf, e1r, e2c, s1, s2, fragb);
  hipLaunchKernelGGL(kB, dim3(NND), dim3(256), 0, stream,
                     x, mask, h, u, vbuf, s1, s2, e1r, e2c,
                     Wcm2, bcm1, bcm2, fragb,
                     Wpn1, bpn1, Wpn2, bpn2, Wnm1, bnm1, Wnm2, bnm2, out);
}

// Round 17
// 53.171 us; speedup vs baseline: 1.8858x; 1.8858x over previous
//
#include <hip/hip_runtime.h>

#define INF 1e10f
#define EPSV 1e-5f
#define NB 2
#define NN 512
#define NF 64
#define NH 64
#define NCC 32
#define NRBF 50
#define NND (NB*NN)
#define MU_STEP (5.0f/49.0f)
#define C20S (20.f*MU_STEP)

typedef _Float16 half8 __attribute__((ext_vector_type(8)));
typedef float f32x4 __attribute__((ext_vector_type(4)));

__device__ __forceinline__ float frcp(float x){ return __builtin_amdgcn_rcpf(x); }
__device__ __forceinline__ float silu_f(float x){ return x * frcp(1.f + __expf(-x)); }
// tanh(x) = 1 - 2/(1+e^{2x}); saturates cleanly at +/-inf (rcp(inf)=0)
__device__ __forceinline__ float tanh_f(float x){
  float t = __expf(2.f * x);
  return fmaf(-2.f, frcp(t + 1.f), 1.f);
}

__device__ __forceinline__ float wredSum(float v){
  v += __shfl_down(v, 32); v += __shfl_down(v, 16); v += __shfl_down(v, 8);
  v += __shfl_down(v, 4);  v += __shfl_down(v, 2);  v += __shfl_down(v, 1);
  return v;
}
__device__ __forceinline__ float bredSum(float v, float* red, int tid){
  float w = wredSum(v);
  __syncthreads();
  if ((tid & 63) == 0) red[tid >> 6] = w;
  __syncthreads();
  return (red[0] + red[1]) + (red[2] + red[3]);
}
__device__ __forceinline__ float2 bredSum2(float a, float b, float* red, int tid){
  float wa = wredSum(a), wb = wredSum(b);
  __syncthreads();
  if ((tid & 63) == 0){ red[(tid >> 6) * 2] = wa; red[(tid >> 6) * 2 + 1] = wb; }
  __syncthreads();
  return make_float2(red[0] + red[2] + red[4] + red[6],
                     red[1] + red[3] + red[5] + red[7]);
}

// -------- Kernel A: per-node projections + fragment packing (fused) -------
// frag: fi 0..7 WfT A-frags (row-permuted so filt C-out == A-frag layout),
//       fi 8..15 Wc1 B-frags, fi 16..19 We3 B-frags
__global__ void kA(const float* __restrict__ h, const float* __restrict__ Wdh,
                   const float* __restrict__ Wew, const float* __restrict__ Wsa,
                   const float* __restrict__ bdh, const float* __restrict__ bew,
                   const float* __restrict__ Wf, const float* __restrict__ bf,
                   const float* __restrict__ Wcm1,
                   float* __restrict__ u, float* __restrict__ vb,
                   float* __restrict__ e1r, float* __restrict__ e2c,
                   float* __restrict__ s1, float* __restrict__ s2,
                   unsigned int* __restrict__ frag){
  const int tid = threadIdx.x;
  const int sub = tid >> 6, l = tid & 63;
  const int node = blockIdx.x * 4 + sub;
  __shared__ float sh[4][NF];
  sh[sub][l] = h[node * NF + l];
  __syncthreads();
  float ua = 0.f, va = 0.f;
  #pragma unroll
  for (int f = 0; f < NF; ++f){
    float hv = sh[sub][f];
    ua = fmaf(hv, Wdh[f * NH + l], ua);
    va = fmaf(hv, Wdh[(NF + f) * NH + l], va);
  }
  u[node * NH + l] = ua;
  vb[node * NH + l] = va + bdh[l];
  const int nc = l & 31;
  const int half = l >> 5;
  float ea = 0.f;
  #pragma unroll
  for (int f = 0; f < NF; ++f) ea = fmaf(sh[sub][f], Wew[(half * NF + f) * NCC + nc], ea);
  if (half == 0) e1r[node * NCC + nc] = ea;
  else           e2c[node * NCC + nc] = ea + bew[nc];
  if (l < 2){
    const float* wp = Wsa + l * NF;
    float s = 0.f;
    #pragma unroll
    for (int f = 0; f < NF; ++f) s = fmaf(sh[sub][f], wp[f], s);
    if (l == 0) s1[node] = s; else s2[node] = s;
  }
  // ---- fragment packing (blocks 0..19 only) ----
  if (blockIdx.x < 20){
    const int fi = blockIdx.x;
    const int lane = tid >> 2, dw = tid & 3;
    float v[2];
    #pragma unroll
    for (int e2 = 0; e2 < 2; ++e2){
      int e = dw * 2 + e2;
      int kk = 8 * (lane >> 4) + e;
      int n16 = lane & 15;
      float val;
      if (fi < 8){
        int mt = fi >> 1, kc = fi & 1;
        int hh = 8 * (n16 >> 2) + (n16 & 3) + 4 * (mt & 1) + 32 * (mt >> 1);
        int r = kk + 32 * kc;
        val = (r < NRBF) ? Wf[r * NH + hh] : ((r == NRBF) ? bf[hh] : 0.f);
      } else if (fi < 16){
        int q = fi - 8; int kc = q >> 2, nt = q & 3;
        val = Wcm1[(kk + 32 * kc) * NH + (n16 + 16 * nt)];
      } else {
        int q = fi - 16; int kc = q >> 1, n2 = q & 1;
        val = Wew[(2 * NF + kk + 32 * kc) * NCC + (n16 + 16 * n2)];
      }
      v[e2] = val;
    }
    unsigned int lo = (unsigned int)__builtin_bit_cast(unsigned short, (_Float16)v[0]);
    unsigned int hi = (unsigned int)__builtin_bit_cast(unsigned short, (_Float16)v[1]);
    frag[fi * 256 + lane * 4 + dw] = lo | (hi << 16);
  }
}

// -------- Kernel B: per-(b,i) edge pass + fused tail MLPs -----------------
__global__ __launch_bounds__(256, 2) void kB(
    const float* __restrict__ x, const float* __restrict__ mask,
    const float* __restrict__ h_g,
    const float* __restrict__ u, const float* __restrict__ vb,
    const float* __restrict__ s1g, const float* __restrict__ s2g,
    const float* __restrict__ e1r, const float* __restrict__ e2c,
    const float* __restrict__ Wc2, const float* __restrict__ bc1, const float* __restrict__ bc2g,
    const unsigned int* __restrict__ frag,
    const float* __restrict__ Wpn1, const float* __restrict__ bpn1,
    const float* __restrict__ Wpn2, const float* __restrict__ bpn2,
    const float* __restrict__ Wnm1, const float* __restrict__ bnm1,
    const float* __restrict__ Wnm2, const float* __restrict__ bnm2,
    float* __restrict__ out)
{
  const int bid = blockIdx.x;
  const int b = bid >> 9, i = bid & (NN - 1);
  const int tid = threadIdx.x;
  const int lane = tid & 63, wave = tid >> 6;
  const int l15 = lane & 15, g = lane >> 4;
  const int base = b * NN;

  __shared__ __align__(16) float4 s_geo[NN];     // d0*m,d1*m,d2*m,norm  8KB
  __shared__ __align__(16) float4 s_c[NN];       // c0,c1,c2,tot*m       8KB
  __shared__ float s_m[NN];                      // 2KB
  __shared__ float s_red[8];
  __shared__ half8 s_WB[20][64];                 // all weight frags 20KB

  // stage all fragments into LDS (1280 int4)
  {
    const int4* src = (const int4*)frag;
    int4* dst = (int4*)&s_WB[0][0];
    #pragma unroll
    for (int q = 0; q < 5; ++q) dst[tid + q * 256] = src[tid + q * 256];
  }

  const float xi0 = x[(base + i) * 3 + 0];
  const float xi1 = x[(base + i) * 3 + 1];
  const float xi2 = x[(base + i) * 3 + 2];
  const float s2i = s2g[base + i];

  // ---- pass 1: bounded logits -> direct exp, 2 reduction rounds ----
  float ea[2], es[2], mj[2];
  #pragma unroll
  for (int q = 0; q < 2; ++q){
    const int j = tid + q * 256;
    float d0 = x[(base + j) * 3 + 0] - xi0;
    float d1 = x[(base + j) * 3 + 1] - xi1;
    float d2 = x[(base + j) * 3 + 2] - xi2;
    float nsq = d0 * d0 + d1 * d1 + d2 * d2;
    float norm = sqrtf(fmaxf(nsq, 0.f) + EPSV);
    float m = mask[(base + i) * NN + j];
    float eye = (j == i) ? 1.f : 0.f;
    // spatial logit <= 0 ; sem logit bounded ; no max-subtraction needed
    ea[q] = __expf(-(norm + eye * INF + (1.f - m) * INF));
    float sp = s1g[base + j] + s2i;
    es[q] = __expf(silu_f(sp) - eye * INF + (m - 1.f) * INF);
    s_geo[j] = make_float4(d0 * m, d1 * m, d2 * m, norm);   // mask folded into d
    s_m[j] = m;
    float inv = frcp(norm * norm + EPSV) * m;
    s_c[j] = make_float4(d0 * inv, d1 * inv, d2 * inv, 0.f);
    mj[q] = m;
  }
  float2 S12 = bredSum2(ea[0] + ea[1], es[0] + es[1], s_red, tid);
  const float iS1 = 1.f / S12.x, iS2 = 1.f / S12.y;
  float e3[2];
  #pragma unroll
  for (int q = 0; q < 2; ++q)
    e3[q] = __expf((es[q] * iS2) * (ea[q] * iS1) + (mj[q] - 1.f) * INF);
  float S3 = bredSum(e3[0] + e3[1], s_red, tid);
  const float iS3 = 1.f / S3;
  s_c[tid].w       = e3[0] * iS3 * mj[0];
  s_c[tid + 256].w = e3[1] * iS3 * mj[1];
  __syncthreads();   // covers pass-1 LDS + s_WB staging

  // ---- per-i prologue ----
  float vba[16];
  {
    const float4* vp = (const float4*)(vb + (size_t)(base + i) * NH);
    float4 a0 = vp[2*g], a1 = vp[2*g+1], a2 = vp[2*g+8], a3 = vp[2*g+9];
    vba[0]=a0.x; vba[1]=a0.y; vba[2]=a0.z; vba[3]=a0.w;
    vba[4]=a1.x; vba[5]=a1.y; vba[6]=a1.z; vba[7]=a1.w;
    vba[8]=a2.x; vba[9]=a2.y; vba[10]=a2.z; vba[11]=a2.w;
    vba[12]=a3.x; vba[13]=a3.y; vba[14]=a3.z; vba[15]=a3.w;
  }
  float wc2v[4], bc1v[4];
  #pragma unroll
  for (int nt = 0; nt < 4; ++nt){ wc2v[nt] = Wc2[l15 + 16*nt]; bc1v[nt] = bc1[l15 + 16*nt]; }
  float e2v[2];
  e2v[0] = e2c[(size_t)(base + i) * NCC + l15];
  e2v[1] = e2c[(size_t)(base + i) * NCC + l15 + 16];
  const float bc2v16 = bc2g[0] * 0.0625f;   // bc2 / 16: added once per edge across 16 lanes
  const float mub0 = (float)(8 * g) * MU_STEP;
  const float mub1 = (float)(8 * g + 32) * MU_STEP;
  // rbf ratio-recurrence constants: e_{r+1} = e_r * rho_r ; rho_{r+1} = rho_r * q
  const float QCONST = __expf(-20.f * MU_STEP * MU_STEP);
  const float crho0 = -10.f * MU_STEP * MU_STEP * (float)(16 * g + 1);
  const float crho1 = -10.f * MU_STEP * MU_STEP * (float)(16 * g + 65);

  float hg[16];
  #pragma unroll
  for (int e = 0; e < 16; ++e) hg[e] = 0.f;
  float at[2][3] = {{0.f,0.f,0.f},{0.f,0.f,0.f}};
  float xa0 = 0.f, xa1 = 0.f, xa2 = 0.f;

  // ---- pass 2: 8 j-tiles of 16 per wave; u software-pipelined ----
  float4 u0, u1, u2, u3;
  {
    const float4* up = (const float4*)(u + (size_t)(base + wave*128 + l15) * NH);
    u0 = up[2*g]; u1 = up[2*g+1]; u2 = up[2*g+8]; u3 = up[2*g+9];
  }

  for (int jt8 = 0; jt8 < 8; ++jt8){
    const int jt = wave * 128 + jt8 * 16;
    const int jl = jt + l15;
    float normj = s_geo[jl].w;
    float tmw = s_c[jl].w;
    // rbf B-frags via ratio recurrence: 4 exps + 28 muls (was 16 exps)
    half8 brb[2];
    {
      float d0 = normj - mub0;
      float d1 = normj - mub1;
      float e0 = __expf(-10.f * d0 * d0);
      float e1 = __expf(-10.f * d1 * d1);
      float r0a = __expf(fmaf(C20S, normj, crho0));
      float r1a = __expf(fmaf(C20S, normj, crho1));
      const int rbase1 = 8*g + 32;
      brb[0][0] = (_Float16)e0;
      brb[1][0] = (_Float16)((rbase1 < NRBF) ? e1 : ((rbase1 == NRBF) ? 1.f : 0.f));
      #pragma unroll
      for (int rr = 1; rr < 8; ++rr){
        e0 *= r0a;  r0a *= QCONST;
        e1 *= r1a;  r1a *= QCONST;
        int r1i = rbase1 + rr;
        brb[0][rr] = (_Float16)e0;
        brb[1][rr] = (_Float16)((r1i < NRBF) ? e1 : ((r1i == NRBF) ? 1.f : 0.f));
      }
    }
    // filtT = WfT(perm) @ rbfT : C-output IS the A-frag layout
    f32x4 fc[4];
    __builtin_amdgcn_s_setprio(1);
    #pragma unroll
    for (int mt = 0; mt < 4; ++mt){
      f32x4 z = {0.f,0.f,0.f,0.f};
      z = __builtin_amdgcn_mfma_f32_16x16x32_f16(s_WB[2*mt][lane],   brb[0], z, 0, 0, 0);
      z = __builtin_amdgcn_mfma_f32_16x16x32_f16(s_WB[2*mt+1][lane], brb[1], z, 0, 0, 0);
      fc[mt] = z;
    }
    __builtin_amdgcn_s_setprio(0);
    // FH = (u + vb) * filt (consumes this tile's u)
    float ua[16] = {u0.x,u0.y,u0.z,u0.w, u1.x,u1.y,u1.z,u1.w,
                    u2.x,u2.y,u2.z,u2.w, u3.x,u3.y,u3.z,u3.w};
    float FH[16];
    half8 afh[2];
    #pragma unroll
    for (int kc = 0; kc < 2; ++kc)
      #pragma unroll
      for (int e = 0; e < 8; ++e){
        int el = kc*8 + e;
        float f = fc[2*kc + (e>>2)][e & 3];
        FH[el] = (ua[el] + vba[el]) * f;
        afh[kc][e] = (_Float16)FH[el];
      }
    // prefetch next tile's u (long gap to its consumption at next FH)
    {
      const int jn = (jt8 < 7) ? (jl + 16) : jl;
      const float4* upn = (const float4*)(u + (size_t)(base + jn) * NH);
      u0 = upn[2*g]; u1 = upn[2*g+1]; u2 = upn[2*g+8]; u3 = upn[2*g+9];
    }
    #pragma unroll
    for (int e = 0; e < 16; ++e) hg[e] = fmaf(tmw, FH[e], hg[e]);
    // e1 loads (consumed by tanh at tile end; issued before MFMAs for latency overlap)
    float e1v[4][2];
    #pragma unroll
    for (int reg = 0; reg < 4; ++reg){
      const float* ep1 = e1r + (size_t)(base + jt + 4*g + reg) * NCC + l15;
      e1v[reg][0] = ep1[0]; e1v[reg][1] = ep1[16];
    }
    // CM = FH @ Wc1 ; EW = FH @ We3 (frags from LDS)
    f32x4 cm[4];
    f32x4 ew[2];
    __builtin_amdgcn_s_setprio(1);
    #pragma unroll
    for (int nt = 0; nt < 4; ++nt){
      f32x4 z = {0.f,0.f,0.f,0.f};
      z = __builtin_amdgcn_mfma_f32_16x16x32_f16(afh[0], s_WB[8+nt][lane],  z, 0, 0, 0);
      z = __builtin_amdgcn_mfma_f32_16x16x32_f16(afh[1], s_WB[12+nt][lane], z, 0, 0, 0);
      cm[nt] = z;
    }
    #pragma unroll
    for (int n2 = 0; n2 < 2; ++n2){
      f32x4 z = {0.f,0.f,0.f,0.f};
      z = __builtin_amdgcn_mfma_f32_16x16x32_f16(afh[0], s_WB[16+n2][lane], z, 0, 0, 0);
      z = __builtin_amdgcn_mfma_f32_16x16x32_f16(afh[1], s_WB[18+n2][lane], z, 0, 0, 0);
      ew[n2] = z;
    }
    __builtin_amdgcn_s_setprio(0);
    float mreg[4]; float4 geo4[4], c4[4];
    #pragma unroll
    for (int reg = 0; reg < 4; ++reg){
      int jr = jt + 4*g + reg;
      mreg[reg] = s_m[jr];
      geo4[reg] = s_geo[jr];     // xyz already mask-premultiplied
      c4[reg]   = s_c[jr];
    }
    // coordinate MLP: silu + dot(Wc2); 16-lane reduce deferred to final xa
    float hEp[4] = {0.f,0.f,0.f,0.f};
    #pragma unroll
    for (int nt = 0; nt < 4; ++nt)
      #pragma unroll
      for (int reg = 0; reg < 4; ++reg){
        float tv = silu_f(fmaf(mreg[reg], cm[nt][reg], bc1v[nt]));
        hEp[reg] = fmaf(tv, wc2v[nt], hEp[reg]);
      }
    #pragma unroll
    for (int reg = 0; reg < 4; ++reg){
      float hv = hEp[reg] + bc2v16;
      xa0 = fmaf(geo4[reg].x, hv, xa0);
      xa1 = fmaf(geo4[reg].y, hv, xa1);
      xa2 = fmaf(geo4[reg].z, hv, xa2);
    }
    // edge weights: tanh + att accumulation
    #pragma unroll
    for (int n2 = 0; n2 < 2; ++n2)
      #pragma unroll
      for (int reg = 0; reg < 4; ++reg){
        float wv = tanh_f(ew[n2][reg] + e1v[reg][n2] + e2v[n2]);
        at[n2][0] = fmaf(wv, c4[reg].x, at[n2][0]);
        at[n2][1] = fmaf(wv, c4[reg].y, at[n2][1]);
        at[n2][2] = fmaf(wv, c4[reg].z, at[n2][2]);
      }
  }

  // ---- reduces ----
  #pragma unroll
  for (int e = 0; e < 16; ++e){
    float v = hg[e];
    v += __shfl_xor(v, 1); v += __shfl_xor(v, 2);
    v += __shfl_xor(v, 4); v += __shfl_xor(v, 8);
    hg[e] = v;
  }
  #pragma unroll
  for (int n2 = 0; n2 < 2; ++n2)
    #pragma unroll
    for (int d = 0; d < 3; ++d){
      float v = at[n2][d];
      v += __shfl_xor(v, 16); v += __shfl_xor(v, 32);
      at[n2][d] = v;
    }
  // xa holds per-lane partials (hEp deferral) -> full 64-lane reduce
  #pragma unroll
  for (int s = 1; s <= 32; s <<= 1){
    xa0 += __shfl_xor(xa0, s);
    xa1 += __shfl_xor(xa1, s);
    xa2 += __shfl_xor(xa2, s);
  }

  // ---- epilogue across waves (alias s_WB; all frag reads done) ----
  __syncthreads();
  float* ep = (float*)&s_WB[0][0];     // 5120 floats available
  if (l15 == 0){
    #pragma unroll
    for (int e = 0; e < 16; ++e)
      ep[wave*64 + 8*g + (e & 7) + 32*(e >> 3)] = hg[e];
  }
  if (lane < 16){
    #pragma unroll
    for (int n2 = 0; n2 < 2; ++n2)
      #pragma unroll
      for (int d = 0; d < 3; ++d)
        ep[256 + wave*96 + (l15 + 16*n2)*3 + d] = at[n2][d];
  }
  if (lane == 0){
    ep[640 + wave*3 + 0] = xa0; ep[640 + wave*3 + 1] = xa1; ep[640 + wave*3 + 2] = xa2;
  }
  __syncthreads();
  if (tid < 64)
    ep[832 + tid] = ep[tid] + ep[64+tid] + ep[128+tid] + ep[192+tid];   // hga -> LDS
  if (tid >= 64 && tid < 160){
    int t = tid - 64;
    ep[704 + t] = ep[256+t] + ep[352+t] + ep[448+t] + ep[544+t];
  }
  if (tid >= 192 && tid < 195){
    int d = tid - 192;
    out[NB*NN*NH + (base + i)*3 + d] =
        ep[640+d] + ep[643+d] + ep[646+d] + ep[649+d] + x[(base + i)*3 + d];
  }
  __syncthreads();
  if (tid < 32){
    float a0 = ep[704 + tid*3], a1 = ep[704 + tid*3 + 1], a2 = ep[704 + tid*3 + 2];
    ep[896 + tid] = sqrtf(fmaxf(a0*a0 + a1*a1 + a2*a2, 0.f) + EPSV);    // attn -> LDS
  }
  __syncthreads();

  // ---- fused tail MLPs (wave 0 only; sa=ep[896..], sg=ep[832..]) ----
  if (wave == 0){
    const int k = lane;
    const int node = base + i;
    ep[1056 + k] = h_g[node * NF + k];
    asm volatile("s_waitcnt lgkmcnt(0)" ::: "memory");
    __builtin_amdgcn_wave_barrier();
    float acc = bpn1[k];
    #pragma unroll
    for (int t = 0; t < NCC; ++t) acc = fmaf(ep[896 + t], Wpn1[t * NH + k], acc);
    ep[928 + k] = silu_f(acc);
    asm volatile("s_waitcnt lgkmcnt(0)" ::: "memory");
    __builtin_amdgcn_wave_barrier();
    acc = bpn2[k];
    #pragma unroll
    for (int t = 0; t < NH; ++t) acc = fmaf(ep[928 + t], Wpn2[t * NH + k], acc);
    ep[992 + k] = acc;                         // emb
    asm volatile("s_waitcnt lgkmcnt(0)" ::: "memory");
    __builtin_amdgcn_wave_barrier();
    acc = bnm1[k];
    #pragma unroll
    for (int t = 0; t < NF; ++t) acc = fmaf(ep[1056 + t], Wnm1[t * NH + k], acc);
    #pragma unroll
    for (int t = 0; t < NH; ++t) acc = fmaf(ep[832 + t],  Wnm1[(NF + t) * NH + k], acc);
    #pragma unroll
    for (int t = 0; t < NH; ++t) acc = fmaf(ep[992 + t],  Wnm1[(NF + NH + t) * NH + k], acc);
    float srv = silu_f(acc);
    asm volatile("s_waitcnt lgkmcnt(0)" ::: "memory");
    __builtin_amdgcn_wave_barrier();
    ep[928 + k] = srv;
    asm volatile("s_waitcnt lgkmcnt(0)" ::: "memory");
    __builtin_amdgcn_wave_barrier();
    acc = bnm2[k];
    #pragma unroll
    for (int t = 0; t < NH; ++t) acc = fmaf(ep[928 + t], Wnm2[t * NH + k], acc);
    out[node * NH + k] = acc;
  }
}

extern "C" void kernel_launch(void* const* d_in, const int* in_sizes, int n_in,
                              void* d_out, int out_size, void* d_ws, size_t ws_size,
                              hipStream_t stream){
  const float* h    = (const float*)d_in[0];
  const float* x    = (const float*)d_in[1];
  const float* mask = (const float*)d_in[2];
  const float* Wdh  = (const float*)d_in[3];
  const float* bdh  = (const float*)d_in[4];
  const float* Wf   = (const float*)d_in[6];
  const float* bf   = (const float*)d_in[7];
  const float* Wsa  = (const float*)d_in[8];
  const float* Wew  = (const float*)d_in[9];
  const float* bew  = (const float*)d_in[10];
  const float* Wpn1 = (const float*)d_in[11];
  const float* bpn1 = (const float*)d_in[12];
  const float* Wpn2 = (const float*)d_in[13];
  const float* bpn2 = (const float*)d_in[14];
  const float* Wnm1 = (const float*)d_in[15];
  const float* bnm1 = (const float*)d_in[16];
  const float* Wnm2 = (const float*)d_in[17];
  const float* bnm2 = (const float*)d_in[18];
  const float* Wcm1 = (const float*)d_in[19];
  const float* bcm1 = (const float*)d_in[20];
  const float* Wcm2 = (const float*)d_in[21];
  const float* bcm2 = (const float*)d_in[22];
  float* out = (float*)d_out;
  float* ws  = (float*)d_ws;

  float* u    = ws;             // [1024][64]
  float* vbuf = u    + 65536;   // [1024][64]
  float* s1   = vbuf + 65536;   // [1024]
  float* s2   = s1   + 1024;    // [1024]
  float* e1r  = s2   + 1024;    // [1024][32]
  float* e2c  = e1r  + 32768;   // [1024][32]
  unsigned int* fragb = (unsigned int*)(e2c + 32768);   // 20*256 u32

  hipLaunchKernelGGL(kA, dim3(NND / 4), dim3(256), 0, stream,
                     h, Wdh, Wew, Wsa, bdh, bew, Wf, bf, Wcm1,
                     u, vbuf, e1r, e2c, s1, s2, fragb);
  hipLaunchKernelGGL(kB, dim3(NND), dim3(256), 0, stream,
                     x, mask, h, u, vbuf, s1, s2, e1r, e2c,
                     Wcm2, bcm1, bcm2, fragb,
                     Wpn1, bpn1, Wpn2, bpn2, Wnm1, bnm1, Wnm2, bnm2, out);
}

// Round 18
// 52.704 us; speedup vs baseline: 1.9025x; 1.0088x over previous
//
#include <hip/hip_runtime.h>

#define INF 1e10f
#define EPSV 1e-5f
#define NB 2
#define NN 512
#define NF 64
#define NH 64
#define NCC 32
#define NRBF 50
#define NND (NB*NN)
#define MU_STEP (5.0f/49.0f)
#define C20S (20.f*MU_STEP)

typedef _Float16 half8 __attribute__((ext_vector_type(8)));
typedef float f32x4 __attribute__((ext_vector_type(4)));

__device__ __forceinline__ float frcp(float x){ return __builtin_amdgcn_rcpf(x); }
__device__ __forceinline__ float silu_f(float x){ return x * frcp(1.f + __expf(-x)); }
// tanh(x) = 1 - 2/(1+e^{2x}); saturates cleanly at +/-inf (rcp(inf)=0)
__device__ __forceinline__ float tanh_f(float x){
  float t = __expf(2.f * x);
  return fmaf(-2.f, frcp(t + 1.f), 1.f);
}

__device__ __forceinline__ float wredSum(float v){
  v += __shfl_down(v, 32); v += __shfl_down(v, 16); v += __shfl_down(v, 8);
  v += __shfl_down(v, 4);  v += __shfl_down(v, 2);  v += __shfl_down(v, 1);
  return v;
}
__device__ __forceinline__ float bredSum(float v, float* red, int tid){
  float w = wredSum(v);
  __syncthreads();
  if ((tid & 63) == 0) red[tid >> 6] = w;
  __syncthreads();
  return (red[0] + red[1]) + (red[2] + red[3]);
}
__device__ __forceinline__ float2 bredSum2(float a, float b, float* red, int tid){
  float wa = wredSum(a), wb = wredSum(b);
  __syncthreads();
  if ((tid & 63) == 0){ red[(tid >> 6) * 2] = wa; red[(tid >> 6) * 2 + 1] = wb; }
  __syncthreads();
  return make_float2(red[0] + red[2] + red[4] + red[6],
                     red[1] + red[3] + red[5] + red[7]);
}

// -------- Kernel A: per-node projections + fragment packing (fused) -------
// frag: fi 0..7 WfT A-frags (row-permuted so filt C-out == A-frag layout),
//       fi 8..15 Wc1 B-frags, fi 16..19 We3 B-frags
__global__ void kA(const float* __restrict__ h, const float* __restrict__ Wdh,
                   const float* __restrict__ Wew, const float* __restrict__ Wsa,
                   const float* __restrict__ bdh, const float* __restrict__ bew,
                   const float* __restrict__ Wf, const float* __restrict__ bf,
                   const float* __restrict__ Wcm1,
                   float* __restrict__ u, float* __restrict__ vb,
                   float* __restrict__ e1r, float* __restrict__ e2c,
                   float* __restrict__ s1, float* __restrict__ s2,
                   unsigned int* __restrict__ frag){
  const int tid = threadIdx.x;
  const int sub = tid >> 6, l = tid & 63;
  const int node = blockIdx.x * 4 + sub;
  __shared__ float sh[4][NF];
  sh[sub][l] = h[node * NF + l];
  __syncthreads();
  float ua = 0.f, va = 0.f;
  #pragma unroll
  for (int f = 0; f < NF; ++f){
    float hv = sh[sub][f];
    ua = fmaf(hv, Wdh[f * NH + l], ua);
    va = fmaf(hv, Wdh[(NF + f) * NH + l], va);
  }
  u[node * NH + l] = ua;
  vb[node * NH + l] = va + bdh[l];
  const int nc = l & 31;
  const int half = l >> 5;
  float ea = 0.f;
  #pragma unroll
  for (int f = 0; f < NF; ++f) ea = fmaf(sh[sub][f], Wew[(half * NF + f) * NCC + nc], ea);
  if (half == 0) e1r[node * NCC + nc] = ea;
  else           e2c[node * NCC + nc] = ea + bew[nc];
  if (l < 2){
    const float* wp = Wsa + l * NF;
    float s = 0.f;
    #pragma unroll
    for (int f = 0; f < NF; ++f) s = fmaf(sh[sub][f], wp[f], s);
    if (l == 0) s1[node] = s; else s2[node] = s;
  }
  // ---- fragment packing (blocks 0..19 only) ----
  if (blockIdx.x < 20){
    const int fi = blockIdx.x;
    const int lane = tid >> 2, dw = tid & 3;
    float v[2];
    #pragma unroll
    for (int e2 = 0; e2 < 2; ++e2){
      int e = dw * 2 + e2;
      int kk = 8 * (lane >> 4) + e;
      int n16 = lane & 15;
      float val;
      if (fi < 8){
        int mt = fi >> 1, kc = fi & 1;
        int hh = 8 * (n16 >> 2) + (n16 & 3) + 4 * (mt & 1) + 32 * (mt >> 1);
        int r = kk + 32 * kc;
        val = (r < NRBF) ? Wf[r * NH + hh] : ((r == NRBF) ? bf[hh] : 0.f);
      } else if (fi < 16){
        int q = fi - 8; int kc = q >> 2, nt = q & 3;
        val = Wcm1[(kk + 32 * kc) * NH + (n16 + 16 * nt)];
      } else {
        int q = fi - 16; int kc = q >> 1, n2 = q & 1;
        val = Wew[(2 * NF + kk + 32 * kc) * NCC + (n16 + 16 * n2)];
      }
      v[e2] = val;
    }
    unsigned int lo = (unsigned int)__builtin_bit_cast(unsigned short, (_Float16)v[0]);
    unsigned int hi = (unsigned int)__builtin_bit_cast(unsigned short, (_Float16)v[1]);
    frag[fi * 256 + lane * 4 + dw] = lo | (hi << 16);
  }
}

// -------- Kernel B: per-(b,i) edge pass + fused tail MLPs -----------------
__global__ __launch_bounds__(256, 2) void kB(
    const float* __restrict__ x, const float* __restrict__ mask,
    const float* __restrict__ h_g,
    const float* __restrict__ u, const float* __restrict__ vb,
    const float* __restrict__ s1g, const float* __restrict__ s2g,
    const float* __restrict__ e1r, const float* __restrict__ e2c,
    const float* __restrict__ Wc2, const float* __restrict__ bc1, const float* __restrict__ bc2g,
    const unsigned int* __restrict__ frag,
    const float* __restrict__ Wpn1, const float* __restrict__ bpn1,
    const float* __restrict__ Wpn2, const float* __restrict__ bpn2,
    const float* __restrict__ Wnm1, const float* __restrict__ bnm1,
    const float* __restrict__ Wnm2, const float* __restrict__ bnm2,
    float* __restrict__ out)
{
  const int bid = blockIdx.x;
  const int b = bid >> 9, i = bid & (NN - 1);
  const int tid = threadIdx.x;
  const int lane = tid & 63, wave = tid >> 6;
  const int l15 = lane & 15, g = lane >> 4;
  const int base = b * NN;

  __shared__ __align__(16) float4 s_geo[NN];     // d0*m,d1*m,d2*m,(m?+:-)norm 8KB
  __shared__ __align__(16) float4 s_c[NN];       // c0,c1,c2,tot*m             8KB
  __shared__ float s_red[8];
  __shared__ half8 s_WB[20][64];                 // all weight frags          20KB

  // stage all fragments into LDS (1280 int4)
  {
    const int4* src = (const int4*)frag;
    int4* dst = (int4*)&s_WB[0][0];
    #pragma unroll
    for (int q = 0; q < 5; ++q) dst[tid + q * 256] = src[tid + q * 256];
  }

  const float xi0 = x[(base + i) * 3 + 0];
  const float xi1 = x[(base + i) * 3 + 1];
  const float xi2 = x[(base + i) * 3 + 2];
  const float s2i = s2g[base + i];

  // ---- pass 1: bounded logits -> direct exp, 2 reduction rounds ----
  float ea[2], es[2], mj[2];
  #pragma unroll
  for (int q = 0; q < 2; ++q){
    const int j = tid + q * 256;
    float d0 = x[(base + j) * 3 + 0] - xi0;
    float d1 = x[(base + j) * 3 + 1] - xi1;
    float d2 = x[(base + j) * 3 + 2] - xi2;
    float nsq = d0 * d0 + d1 * d1 + d2 * d2;
    float norm = sqrtf(fmaxf(nsq, 0.f) + EPSV);
    float m = mask[(base + i) * NN + j];
    float eye = (j == i) ? 1.f : 0.f;
    // spatial logit <= 0 ; sem logit bounded ; no max-subtraction needed
    ea[q] = __expf(-(norm + eye * INF + (1.f - m) * INF));
    float sp = s1g[base + j] + s2i;
    es[q] = __expf(silu_f(sp) - eye * INF + (m - 1.f) * INF);
    // mask folded into d; m sign-encoded into norm slot
    s_geo[j] = make_float4(d0 * m, d1 * m, d2 * m, (m > 0.5f) ? norm : -norm);
    float inv = frcp(norm * norm + EPSV) * m;
    s_c[j] = make_float4(d0 * inv, d1 * inv, d2 * inv, 0.f);
    mj[q] = m;
  }
  float2 S12 = bredSum2(ea[0] + ea[1], es[0] + es[1], s_red, tid);
  const float iS1 = frcp(S12.x), iS2 = frcp(S12.y);
  float e3[2];
  #pragma unroll
  for (int q = 0; q < 2; ++q)
    e3[q] = __expf((es[q] * iS2) * (ea[q] * iS1) + (mj[q] - 1.f) * INF);
  float S3 = bredSum(e3[0] + e3[1], s_red, tid);
  const float iS3 = frcp(S3);
  s_c[tid].w       = e3[0] * iS3 * mj[0];
  s_c[tid + 256].w = e3[1] * iS3 * mj[1];
  __syncthreads();   // covers pass-1 LDS + s_WB staging

  // ---- per-i prologue ----
  float vba[16];
  {
    const float4* vp = (const float4*)(vb + (size_t)(base + i) * NH);
    float4 a0 = vp[2*g], a1 = vp[2*g+1], a2 = vp[2*g+8], a3 = vp[2*g+9];
    vba[0]=a0.x; vba[1]=a0.y; vba[2]=a0.z; vba[3]=a0.w;
    vba[4]=a1.x; vba[5]=a1.y; vba[6]=a1.z; vba[7]=a1.w;
    vba[8]=a2.x; vba[9]=a2.y; vba[10]=a2.z; vba[11]=a2.w;
    vba[12]=a3.x; vba[13]=a3.y; vba[14]=a3.z; vba[15]=a3.w;
  }
  float wc2v[4], bc1v[4];
  #pragma unroll
  for (int nt = 0; nt < 4; ++nt){ wc2v[nt] = Wc2[l15 + 16*nt]; bc1v[nt] = bc1[l15 + 16*nt]; }
  float e2v[2];
  e2v[0] = e2c[(size_t)(base + i) * NCC + l15];
  e2v[1] = e2c[(size_t)(base + i) * NCC + l15 + 16];
  const float bc2v16 = bc2g[0] * 0.0625f;   // bc2 / 16: added once per edge across 16 lanes
  const float mub0 = (float)(8 * g) * MU_STEP;
  const float mub1 = (float)(8 * g + 32) * MU_STEP;
  // rbf ratio-recurrence constants: e_{r+1} = e_r * rho_r ; rho_{r+1} = rho_r * q
  const float QCONST = __expf(-20.f * MU_STEP * MU_STEP);
  const float crho0 = -10.f * MU_STEP * MU_STEP * (float)(16 * g + 1);
  const float crho1 = -10.f * MU_STEP * MU_STEP * (float)(16 * g + 65);

  float hg[16];
  #pragma unroll
  for (int e = 0; e < 16; ++e) hg[e] = 0.f;
  float at[2][3] = {{0.f,0.f,0.f},{0.f,0.f,0.f}};
  float xa0 = 0.f, xa1 = 0.f, xa2 = 0.f;

  // ---- pass 2: 8 j-tiles of 16 per wave; u software-pipelined ----
  float4 u0, u1, u2, u3;
  {
    const float4* up = (const float4*)(u + (size_t)(base + wave*128 + l15) * NH);
    u0 = up[2*g]; u1 = up[2*g+1]; u2 = up[2*g+8]; u3 = up[2*g+9];
  }

  for (int jt8 = 0; jt8 < 8; ++jt8){
    const int jt = wave * 128 + jt8 * 16;
    const int jl = jt + l15;
    float normj = fabsf(s_geo[jl].w);
    float tmw = s_c[jl].w;
    // rbf B-frags via ratio recurrence: 4 exps + 28 muls
    half8 brb[2];
    {
      float d0 = normj - mub0;
      float d1 = normj - mub1;
      float e0 = __expf(-10.f * d0 * d0);
      float e1 = __expf(-10.f * d1 * d1);
      float r0a = __expf(fmaf(C20S, normj, crho0));
      float r1a = __expf(fmaf(C20S, normj, crho1));
      const int rbase1 = 8*g + 32;
      brb[0][0] = (_Float16)e0;
      brb[1][0] = (_Float16)((rbase1 < NRBF) ? e1 : ((rbase1 == NRBF) ? 1.f : 0.f));
      #pragma unroll
      for (int rr = 1; rr < 8; ++rr){
        e0 *= r0a;  r0a *= QCONST;
        e1 *= r1a;  r1a *= QCONST;
        int r1i = rbase1 + rr;
        brb[0][rr] = (_Float16)e0;
        brb[1][rr] = (_Float16)((r1i < NRBF) ? e1 : ((r1i == NRBF) ? 1.f : 0.f));
      }
    }
    // filtT = WfT(perm) @ rbfT : C-output IS the A-frag layout
    f32x4 fc[4];
    __builtin_amdgcn_s_setprio(1);
    #pragma unroll
    for (int mt = 0; mt < 4; ++mt){
      f32x4 z = {0.f,0.f,0.f,0.f};
      z = __builtin_amdgcn_mfma_f32_16x16x32_f16(s_WB[2*mt][lane],   brb[0], z, 0, 0, 0);
      z = __builtin_amdgcn_mfma_f32_16x16x32_f16(s_WB[2*mt+1][lane], brb[1], z, 0, 0, 0);
      fc[mt] = z;
    }
    __builtin_amdgcn_s_setprio(0);
    // FH = (u + vb) * filt (consumes this tile's u)
    float ua[16] = {u0.x,u0.y,u0.z,u0.w, u1.x,u1.y,u1.z,u1.w,
                    u2.x,u2.y,u2.z,u2.w, u3.x,u3.y,u3.z,u3.w};
    float FH[16];
    half8 afh[2];
    #pragma unroll
    for (int kc = 0; kc < 2; ++kc)
      #pragma unroll
      for (int e = 0; e < 8; ++e){
        int el = kc*8 + e;
        float f = fc[2*kc + (e>>2)][e & 3];
        FH[el] = (ua[el] + vba[el]) * f;
        afh[kc][e] = (_Float16)FH[el];
      }
    // prefetch next tile's u (long gap to its consumption at next FH)
    {
      const int jn = (jt8 < 7) ? (jl + 16) : jl;
      const float4* upn = (const float4*)(u + (size_t)(base + jn) * NH);
      u0 = upn[2*g]; u1 = upn[2*g+1]; u2 = upn[2*g+8]; u3 = upn[2*g+9];
    }
    #pragma unroll
    for (int e = 0; e < 16; ++e) hg[e] = fmaf(tmw, FH[e], hg[e]);
    // e1 loads (consumed by tanh at tile end; issued before MFMAs for latency overlap)
    float e1v[4][2];
    #pragma unroll
    for (int reg = 0; reg < 4; ++reg){
      const float* ep1 = e1r + (size_t)(base + jt + 4*g + reg) * NCC + l15;
      e1v[reg][0] = ep1[0]; e1v[reg][1] = ep1[16];
    }
    // CM = FH @ Wc1 ; EW = FH @ We3 (frags from LDS)
    f32x4 cm[4];
    f32x4 ew[2];
    __builtin_amdgcn_s_setprio(1);
    #pragma unroll
    for (int nt = 0; nt < 4; ++nt){
      f32x4 z = {0.f,0.f,0.f,0.f};
      z = __builtin_amdgcn_mfma_f32_16x16x32_f16(afh[0], s_WB[8+nt][lane],  z, 0, 0, 0);
      z = __builtin_amdgcn_mfma_f32_16x16x32_f16(afh[1], s_WB[12+nt][lane], z, 0, 0, 0);
      cm[nt] = z;
    }
    #pragma unroll
    for (int n2 = 0; n2 < 2; ++n2){
      f32x4 z = {0.f,0.f,0.f,0.f};
      z = __builtin_amdgcn_mfma_f32_16x16x32_f16(afh[0], s_WB[16+n2][lane], z, 0, 0, 0);
      z = __builtin_amdgcn_mfma_f32_16x16x32_f16(afh[1], s_WB[18+n2][lane], z, 0, 0, 0);
      ew[n2] = z;
    }
    __builtin_amdgcn_s_setprio(0);
    float mreg[4]; float4 geo4[4], c4[4];
    #pragma unroll
    for (int reg = 0; reg < 4; ++reg){
      int jr = jt + 4*g + reg;
      geo4[reg] = s_geo[jr];                      // xyz mask-premultiplied
      mreg[reg] = (geo4[reg].w > 0.f) ? 1.f : 0.f; // decode m from sign
      c4[reg]   = s_c[jr];
    }
    // coordinate MLP: silu + dot(Wc2); 16-lane reduce deferred to final xa
    float hEp[4] = {0.f,0.f,0.f,0.f};
    #pragma unroll
    for (int nt = 0; nt < 4; ++nt)
      #pragma unroll
      for (int reg = 0; reg < 4; ++reg){
        float tv = silu_f(fmaf(mreg[reg], cm[nt][reg], bc1v[nt]));
        hEp[reg] = fmaf(tv, wc2v[nt], hEp[reg]);
      }
    #pragma unroll
    for (int reg = 0; reg < 4; ++reg){
      float hv = hEp[reg] + bc2v16;
      xa0 = fmaf(geo4[reg].x, hv, xa0);
      xa1 = fmaf(geo4[reg].y, hv, xa1);
      xa2 = fmaf(geo4[reg].z, hv, xa2);
    }
    // edge weights: tanh + att accumulation
    #pragma unroll
    for (int n2 = 0; n2 < 2; ++n2)
      #pragma unroll
      for (int reg = 0; reg < 4; ++reg){
        float wv = tanh_f(ew[n2][reg] + e1v[reg][n2] + e2v[n2]);
        at[n2][0] = fmaf(wv, c4[reg].x, at[n2][0]);
        at[n2][1] = fmaf(wv, c4[reg].y, at[n2][1]);
        at[n2][2] = fmaf(wv, c4[reg].z, at[n2][2]);
      }
  }

  // ---- reduces ----
  #pragma unroll
  for (int e = 0; e < 16; ++e){
    float v = hg[e];
    v += __shfl_xor(v, 1); v += __shfl_xor(v, 2);
    v += __shfl_xor(v, 4); v += __shfl_xor(v, 8);
    hg[e] = v;
  }
  #pragma unroll
  for (int n2 = 0; n2 < 2; ++n2)
    #pragma unroll
    for (int d = 0; d < 3; ++d){
      float v = at[n2][d];
      v += __shfl_xor(v, 16); v += __shfl_xor(v, 32);
      at[n2][d] = v;
    }
  // xa holds per-lane partials (hEp deferral) -> full 64-lane reduce
  #pragma unroll
  for (int s = 1; s <= 32; s <<= 1){
    xa0 += __shfl_xor(xa0, s);
    xa1 += __shfl_xor(xa1, s);
    xa2 += __shfl_xor(xa2, s);
  }

  // ---- epilogue across waves (alias s_WB; all frag reads done) ----
  __syncthreads();
  float* ep = (float*)&s_WB[0][0];     // 5120 floats available
  if (l15 == 0){
    #pragma unroll
    for (int e = 0; e < 16; ++e)
      ep[wave*64 + 8*g + (e & 7) + 32*(e >> 3)] = hg[e];
  }
  if (lane < 16){
    #pragma unroll
    for (int n2 = 0; n2 < 2; ++n2)
      #pragma unroll
      for (int d = 0; d < 3; ++d)
        ep[256 + wave*96 + (l15 + 16*n2)*3 + d] = at[n2][d];
  }
  if (lane == 0){
    ep[640 + wave*3 + 0] = xa0; ep[640 + wave*3 + 1] = xa1; ep[640 + wave*3 + 2] = xa2;
  }
  __syncthreads();
  if (tid < 64)
    ep[832 + tid] = ep[tid] + ep[64+tid] + ep[128+tid] + ep[192+tid];   // hga -> LDS
  if (tid >= 64 && tid < 160){
    int t = tid - 64;
    ep[704 + t] = ep[256+t] + ep[352+t] + ep[448+t] + ep[544+t];
  }
  if (tid >= 192 && tid < 195){
    int d = tid - 192;
    out[NB*NN*NH + (base + i)*3 + d] =
        ep[640+d] + ep[643+d] + ep[646+d] + ep[649+d] + x[(base + i)*3 + d];
  }
  __syncthreads();
  if (tid < 32){
    float a0 = ep[704 + tid*3], a1 = ep[704 + tid*3 + 1], a2 = ep[704 + tid*3 + 2];
    ep[896 + tid] = sqrtf(fmaxf(a0*a0 + a1*a1 + a2*a2, 0.f) + EPSV);    // attn -> LDS
  }
  __syncthreads();

  // ---- fused tail MLPs (wave 0 only; sa=ep[896..], sg=ep[832..]) ----
  if (wave == 0){
    const int k = lane;
    const int node = base + i;
    ep[1056 + k] = h_g[node * NF + k];
    asm volatile("s_waitcnt lgkmcnt(0)" ::: "memory");
    __builtin_amdgcn_wave_barrier();
    float acc = bpn1[k];
    #pragma unroll
    for (int t = 0; t < NCC; ++t) acc = fmaf(ep[896 + t], Wpn1[t * NH + k], acc);
    ep[928 + k] = silu_f(acc);
    asm volatile("s_waitcnt lgkmcnt(0)" ::: "memory");
    __builtin_amdgcn_wave_barrier();
    acc = bpn2[k];
    #pragma unroll
    for (int t = 0; t < NH; ++t) acc = fmaf(ep[928 + t], Wpn2[t * NH + k], acc);
    ep[992 + k] = acc;                         // emb
    asm volatile("s_waitcnt lgkmcnt(0)" ::: "memory");
    __builtin_amdgcn_wave_barrier();
    acc = bnm1[k];
    #pragma unroll
    for (int t = 0; t < NF; ++t) acc = fmaf(ep[1056 + t], Wnm1[t * NH + k], acc);
    #pragma unroll
    for (int t = 0; t < NH; ++t) acc = fmaf(ep[832 + t],  Wnm1[(NF + t) * NH + k], acc);
    #pragma unroll
    for (int t = 0; t < NH; ++t) acc = fmaf(ep[992 + t],  Wnm1[(NF + NH + t) * NH + k], acc);
    float srv = silu_f(acc);
    asm volatile("s_waitcnt lgkmcnt(0)" ::: "memory");
    __builtin_amdgcn_wave_barrier();
    ep[928 + k] = srv;
    asm volatile("s_waitcnt lgkmcnt(0)" ::: "memory");
    __builtin_amdgcn_wave_barrier();
    acc = bnm2[k];
    #pragma unroll
    for (int t = 0; t < NH; ++t) acc = fmaf(ep[928 + t], Wnm2[t * NH + k], acc);
    out[node * NH + k] = acc;
  }
}

extern "C" void kernel_launch(void* const* d_in, const int* in_sizes, int n_in,
                              void* d_out, int out_size, void* d_ws, size_t ws_size,
                              hipStream_t stream){
  const float* h    = (const float*)d_in[0];
  const float* x    = (const float*)d_in[1];
  const float* mask = (const float*)d_in[2];
  const float* Wdh  = (const float*)d_in[3];
  const float* bdh  = (const float*)d_in[4];
  const float* Wf   = (const float*)d_in[6];
  const float* bf   = (const float*)d_in[7];
  const float* Wsa  = (const float*)d_in[8];
  const float* Wew  = (const float*)d_in[9];
  const float* bew  = (const float*)d_in[10];
  const float* Wpn1 = (const float*)d_in[11];
  const float* bpn1 = (const float*)d_in[12];
  const float* Wpn2 = (const float*)d_in[13];
  const float* bpn2 = (const float*)d_in[14];
  const float* Wnm1 = (const float*)d_in[15];
  const float* bnm1 = (const float*)d_in[16];
  const float* Wnm2 = (const float*)d_in[17];
  const float* bnm2 = (const float*)d_in[18];
  const float* Wcm1 = (const float*)d_in[19];
  const float* bcm1 = (const float*)d_in[20];
  const float* Wcm2 = (const float*)d_in[21];
  const float* bcm2 = (const float*)d_in[22];
  float* out = (float*)d_out;
  float* ws  = (float*)d_ws;

  float* u    = ws;             // [1024][64]
  float* vbuf = u    + 65536;   // [1024][64]
  float* s1   = vbuf + 65536;   // [1024]
  float* s2   = s1   + 1024;    // [1024]
  float* e1r  = s2   + 1024;    // [1024][32]
  float* e2c  = e1r  + 32768;   // [1024][32]
  unsigned int* fragb = (unsigned int*)(e2c + 32768);   // 20*256 u32

  hipLaunchKernelGGL(kA, dim3(NND / 4), dim3(256), 0, stream,
                     h, Wdh, Wew, Wsa, bdh, bew, Wf, bf, Wcm1,
                     u, vbuf, e1r, e2c, s1, s2, fragb);
  hipLaunchKernelGGL(kB, dim3(NND), dim3(256), 0, stream,
                     x, mask, h, u, vbuf, s1, s2, e1r, e2c,
                     Wcm2, bcm1, bcm2, fragb,
                     Wpn1, bpn1, Wpn2, bpn2, Wnm1, bnm1, Wnm2, bnm2, out);
}